// Round 4
// baseline (299.556 us; speedup 1.0000x reference)
//
#include <hip/hip_runtime.h>

// Exact-match lookup of 4M int32 queries in a sorted 8M int32 key table.
// Round 4: same packed 16B bucket table (shift=8, B=2^23, 128 MB), but the
// build is inverted to one-thread-per-bucket with block-windowed binary
// search -> fully coalesced table stores, no divergent gap-fill loops.
//
// Entry format (4 x 32-bit slots per bucket; keys in a bucket share bits
// [30:8], values verified < 2^20 at build time):
//   bits[31:28] flags: 0=empty, 1=valid pair, 2=overflow descriptor (word0)
//   bits[27:8]  value
//   bits[7:0]   low 8 bits of key
// Overflow (count>4 or value out of range): word0 = 2<<28, word1 = start.
// Lookup scans keys/vals from start with early exit on key >= q (sorted keys
// in later buckets are > q, so the scan always terminates correctly).
// Slots are filled in sorted order and checked in order -> searchsorted-left
// semantics for duplicate keys.

__device__ __forceinline__ int lower_bound_u(const int* __restrict__ keys,
                                             int lo, int hi, unsigned t) {
    while (lo < hi) {
        int m = (lo + hi) >> 1;
        if ((unsigned)keys[m] < t) lo = m + 1; else hi = m;
    }
    return lo;
}

__global__ void build_packed2_kernel(const int* __restrict__ keys,
                                     const int* __restrict__ vals, int K,
                                     int4* __restrict__ table) {
    __shared__ int s_range[2];
    unsigned b0 = (unsigned)blockIdx.x * 256u;
    if (threadIdx.x < 2) {
        unsigned t = (b0 + threadIdx.x * 256u) << 8;  // (b0+256)<<8 == 2^31 max, ok unsigned
        s_range[threadIdx.x] = lower_bound_u(keys, 0, K, t);
    }
    __syncthreads();
    int wlo = s_range[0], whi = s_range[1];

    unsigned b = b0 + threadIdx.x;
    unsigned tlo = b << 8;
    unsigned thi = (b + 1u) << 8;

    int lo = lower_bound_u(keys, wlo, whi, tlo);

    int w[4] = {0, 0, 0, 0};
    bool ok = true;
    int cnt = 0;
    int j = lo;
    while (j < whi && (unsigned)keys[j] < thi) {
        if (cnt >= 4) { ok = false; break; }
        int v = vals[j];
        if ((unsigned)v > 0xFFFFFu) { ok = false; break; }
        w[cnt] = (1 << 28) | (v << 8) | (keys[j] & 0xFF);
        ++cnt; ++j;
    }
    int4 e = ok ? make_int4(w[0], w[1], w[2], w[3])
                : make_int4(2 << 28, lo, 0, 0);
    table[b] = e;
}

__device__ __forceinline__ int resolve_packed(int q, int4 e,
                                              const int* __restrict__ keys,
                                              const int* __restrict__ vals,
                                              int K) {
    if ((((unsigned)e.x) >> 28) == 2u) {  // overflow: scan original arrays
        for (int j = e.y; j < K; ++j) {
            int k = keys[j];
            if ((unsigned)k >= (unsigned)q) return (k == q) ? vals[j] : -1;
        }
        return -1;
    }
    int ql = q & 0xFF;
    int w;
    w = e.x; if ((((unsigned)w) >> 28) == 1u && (w & 0xFF) == ql) return (w >> 8) & 0xFFFFF;
    w = e.y; if ((((unsigned)w) >> 28) == 1u && (w & 0xFF) == ql) return (w >> 8) & 0xFFFFF;
    w = e.z; if ((((unsigned)w) >> 28) == 1u && (w & 0xFF) == ql) return (w >> 8) & 0xFFFFF;
    w = e.w; if ((((unsigned)w) >> 28) == 1u && (w & 0xFF) == ql) return (w >> 8) & 0xFFFFF;
    return -1;
}

__global__ void lookup_packed_kernel(const int* __restrict__ query,
                                     const int* __restrict__ keys,
                                     const int* __restrict__ vals,
                                     const int4* __restrict__ table,
                                     int* __restrict__ out,
                                     int N, int K, unsigned Bmask) {
    int half = (N + 1) >> 1;
    int i = blockIdx.x * blockDim.x + threadIdx.x;
    if (i >= half) return;
    // two independent probe chains per thread for memory-level parallelism
    int i1 = i + half;
    bool has1 = (i1 < N);
    int q0 = query[i];
    int q1 = has1 ? query[i1] : q0;
    int4 e0 = table[(((unsigned)q0) >> 8) & Bmask];
    int4 e1 = table[(((unsigned)q1) >> 8) & Bmask];
    out[i] = resolve_packed(q0, e0, keys, vals, K);
    if (has1) out[i1] = resolve_packed(q1, e1, keys, vals, K);
}

// Fallback for tiny workspace: plain binary search (searchsorted 'left').
__global__ void lookup_bsearch_kernel(const int* __restrict__ query,
                                      const int* __restrict__ keys,
                                      const int* __restrict__ vals,
                                      int* __restrict__ out,
                                      int N, int K) {
    int i = blockIdx.x * blockDim.x + threadIdx.x;
    if (i >= N) return;
    int q = query[i];
    int lo = lower_bound_u(keys, 0, K, (unsigned)q);
    int r = -1;
    if (lo < K && keys[lo] == q) r = vals[lo];
    out[i] = r;
}

extern "C" void kernel_launch(void* const* d_in, const int* in_sizes, int n_in,
                              void* d_out, int out_size, void* d_ws, size_t ws_size,
                              hipStream_t stream) {
    const int* query = (const int*)d_in[0];
    const int* keys  = (const int*)d_in[1];
    const int* vals  = (const int*)d_in[2];
    int* out = (int*)d_out;
    const int N = in_sizes[0];
    const int K = in_sizes[1];
    const int tb = 256;

    if (((size_t)16 << 23) <= ws_size) {
        // packed path: B = 2^23 buckets (shift 8), 16B/bucket = 128 MB
        const unsigned B = 1u << 23;
        int4* table = (int4*)d_ws;
        build_packed2_kernel<<<B / tb, tb, 0, stream>>>(keys, vals, K, table);
        int half = (N + 1) >> 1;
        lookup_packed_kernel<<<(half + tb - 1) / tb, tb, 0, stream>>>(
            query, keys, vals, table, out, N, K, B - 1);
    } else {
        lookup_bsearch_kernel<<<(N + tb - 1) / tb, tb, 0, stream>>>(query, keys,
                                                                    vals, out, N, K);
    }
}

// Round 5
// 163.403 us; speedup vs baseline: 1.8332x; 1.8332x over previous
//
#include <hip/hip_runtime.h>

// Exact-match lookup of 4M int32 queries in a sorted 8M int32 key table.
// Round 5: same packed 16B bucket table (shift=8, B=2^23, 128 MB). Build is
// split into (a) a block-window index kernel (independent binary searches,
// one per 256-bucket block) and (b) an LDS-staged per-bucket pack kernel with
// fully coalesced loads and stores. Lookup unchanged.
//
// Entry format (4 x 32-bit slots per bucket; keys in a bucket share bits
// [30:8], values verified < 2^20 at build time):
//   bits[31:28] flags: 0=empty, 1=valid pair, 2=overflow descriptor (word0)
//   bits[27:8]  value
//   bits[7:0]   low 8 bits of key
// Overflow (count>4 or value out of range): word0 = 2<<28, word1 = start.
// Lookup scans keys/vals from start with early exit on key >= q.
// Slots filled in sorted order, checked in order -> searchsorted-left.

constexpr int WCAP = 1024;   // LDS window capacity per 256-bucket block
constexpr int NBLK = 1 << 15;  // 32768 build blocks (256 buckets each)

__device__ __forceinline__ int lower_bound_u(const int* __restrict__ keys,
                                             int lo, int hi, unsigned t) {
    while (lo < hi) {
        int m = (lo + hi) >> 1;
        if ((unsigned)keys[m] < t) lo = m + 1; else hi = m;
    }
    return lo;
}

// bstart[i] = lower_bound(keys, i<<16), i in [0, NBLK] inclusive.
__global__ void block_index_kernel(const int* __restrict__ keys, int K,
                                   int* __restrict__ bstart) {
    int i = blockIdx.x * blockDim.x + threadIdx.x;
    if (i > NBLK) return;
    bstart[i] = lower_bound_u(keys, 0, K, ((unsigned)i) << 16);
}

__global__ void __launch_bounds__(256) build_packed3_kernel(
        const int* __restrict__ keys, const int* __restrict__ vals, int K,
        const int* __restrict__ bstart, int4* __restrict__ table) {
    __shared__ int s_keys[WCAP];
    __shared__ int s_vals[WCAP];
    int wlo = bstart[blockIdx.x];
    int whi = bstart[blockIdx.x + 1];
    int wn = whi - wlo;
    bool use_lds = (wn <= WCAP);   // block-uniform
    if (use_lds) {
        for (int j = threadIdx.x; j < wn; j += 256) {
            s_keys[j] = keys[wlo + j];
            s_vals[j] = vals[wlo + j];
        }
    }
    __syncthreads();

    unsigned b = (unsigned)blockIdx.x * 256u + threadIdx.x;
    unsigned tlo = b << 8;
    unsigned thi = tlo + 256u;

    int w[4] = {0, 0, 0, 0};
    bool ok = true;
    int cnt = 0;
    int lo_global;

    if (use_lds) {
        int l = 0, h = wn;
        while (l < h) {
            int m = (l + h) >> 1;
            if ((unsigned)s_keys[m] < tlo) l = m + 1; else h = m;
        }
        lo_global = wlo + l;
        int j = l;
        while (j < wn && (unsigned)s_keys[j] < thi) {
            if (cnt >= 4) { ok = false; break; }
            int v = s_vals[j];
            if ((unsigned)v > 0xFFFFFu) { ok = false; break; }
            w[cnt] = (1 << 28) | (v << 8) | (s_keys[j] & 0xFF);
            ++cnt; ++j;
        }
    } else {  // statistically-never fallback: window too big for LDS
        int l = lower_bound_u(keys, wlo, whi, tlo);
        lo_global = l;
        int j = l;
        while (j < whi && (unsigned)keys[j] < thi) {
            if (cnt >= 4) { ok = false; break; }
            int v = vals[j];
            if ((unsigned)v > 0xFFFFFu) { ok = false; break; }
            w[cnt] = (1 << 28) | (v << 8) | (keys[j] & 0xFF);
            ++cnt; ++j;
        }
    }
    table[b] = ok ? make_int4(w[0], w[1], w[2], w[3])
                  : make_int4(2 << 28, lo_global, 0, 0);
}

__device__ __forceinline__ int resolve_packed(int q, int4 e,
                                              const int* __restrict__ keys,
                                              const int* __restrict__ vals,
                                              int K) {
    if ((((unsigned)e.x) >> 28) == 2u) {  // overflow: scan original arrays
        for (int j = e.y; j < K; ++j) {
            int k = keys[j];
            if ((unsigned)k >= (unsigned)q) return (k == q) ? vals[j] : -1;
        }
        return -1;
    }
    int ql = q & 0xFF;
    int w;
    w = e.x; if ((((unsigned)w) >> 28) == 1u && (w & 0xFF) == ql) return (w >> 8) & 0xFFFFF;
    w = e.y; if ((((unsigned)w) >> 28) == 1u && (w & 0xFF) == ql) return (w >> 8) & 0xFFFFF;
    w = e.z; if ((((unsigned)w) >> 28) == 1u && (w & 0xFF) == ql) return (w >> 8) & 0xFFFFF;
    w = e.w; if ((((unsigned)w) >> 28) == 1u && (w & 0xFF) == ql) return (w >> 8) & 0xFFFFF;
    return -1;
}

__global__ void lookup_packed_kernel(const int* __restrict__ query,
                                     const int* __restrict__ keys,
                                     const int* __restrict__ vals,
                                     const int4* __restrict__ table,
                                     int* __restrict__ out,
                                     int N, int K, unsigned Bmask) {
    int half = (N + 1) >> 1;
    int i = blockIdx.x * blockDim.x + threadIdx.x;
    if (i >= half) return;
    int i1 = i + half;
    bool has1 = (i1 < N);
    int q0 = query[i];
    int q1 = has1 ? query[i1] : q0;
    int4 e0 = table[(((unsigned)q0) >> 8) & Bmask];
    int4 e1 = table[(((unsigned)q1) >> 8) & Bmask];
    out[i] = resolve_packed(q0, e0, keys, vals, K);
    if (has1) out[i1] = resolve_packed(q1, e1, keys, vals, K);
}

// Fallback for tiny workspace: plain binary search (searchsorted 'left').
__global__ void lookup_bsearch_kernel(const int* __restrict__ query,
                                      const int* __restrict__ keys,
                                      const int* __restrict__ vals,
                                      int* __restrict__ out,
                                      int N, int K) {
    int i = blockIdx.x * blockDim.x + threadIdx.x;
    if (i >= N) return;
    int q = query[i];
    int lo = lower_bound_u(keys, 0, K, (unsigned)q);
    int r = -1;
    if (lo < K && keys[lo] == q) r = vals[lo];
    out[i] = r;
}

extern "C" void kernel_launch(void* const* d_in, const int* in_sizes, int n_in,
                              void* d_out, int out_size, void* d_ws, size_t ws_size,
                              hipStream_t stream) {
    const int* query = (const int*)d_in[0];
    const int* keys  = (const int*)d_in[1];
    const int* vals  = (const int*)d_in[2];
    int* out = (int*)d_out;
    const int N = in_sizes[0];
    const int K = in_sizes[1];
    const int tb = 256;

    const size_t TABLE_BYTES = (size_t)16 << 23;       // 128 MB
    const size_t IDX_BYTES   = (size_t)(NBLK + 1) * 4; // ~128 KB

    if (TABLE_BYTES <= ws_size) {
        const unsigned B = 1u << 23;
        int4* table = (int4*)d_ws;
        // Block index: ws tail if it fits, else d_out (scratch is legal:
        // lookup fully overwrites d_out afterwards; deterministic per call).
        int* bstart = (TABLE_BYTES + IDX_BYTES <= ws_size)
                          ? (int*)((char*)d_ws + TABLE_BYTES)
                          : (int*)d_out;
        block_index_kernel<<<(NBLK + 1 + tb - 1) / tb, tb, 0, stream>>>(keys, K, bstart);
        build_packed3_kernel<<<NBLK, tb, 0, stream>>>(keys, vals, K, bstart, table);
        int half = (N + 1) >> 1;
        lookup_packed_kernel<<<(half + tb - 1) / tb, tb, 0, stream>>>(
            query, keys, vals, table, out, N, K, B - 1);
    } else {
        lookup_bsearch_kernel<<<(N + tb - 1) / tb, tb, 0, stream>>>(query, keys,
                                                                    vals, out, N, K);
    }
}